// Round 14
// baseline (134.994 us; speedup 1.0000x reference)
//
#include <hip/hip_runtime.h>
#include <math.h>

#define NPTS   2048      // N
#define LFEAT  56        // C*L
#define HFEAT  128       // H
#define HALFW  8
#define NEIGH  17
#define BR     32        // rows per block (chunk within one batch)
#define BAND   48        // BR + 2*HALFW
#define LDW    132       // f-row pad: 132 floats

// ---------------------------------------------------------------------------
// Fused, LDS-minimal feature phase:
//  1. stage raw x_mem band (PV source) into LDS, coalesced
//  2. features: lane j holds x[row][j] (coalesced global load, 1/row);
//     broadcast via compile-time __shfl (v_readlane, VALU-only); weight
//     column (h = (wave&1)*64+lane) in 56 VGPRs; write f to LDS (1 ds_write)
//  3. QK / softmax / PV / blend: identical to round 13 (fm/fi from LDS,
//     xm from LDS, blend reads x_in global)
// ---------------------------------------------------------------------------
__global__ __launch_bounds__(512) void fused_kernel(
    const float* __restrict__ x_in, const float* __restrict__ x_mem,
    const float* __restrict__ conv_w, const float* __restrict__ conv_b,
    const float* __restrict__ gamma,  const float* __restrict__ beta,
    const float* __restrict__ bmean,  const float* __restrict__ bvar,
    float* __restrict__ out, int R)
{
    __shared__ float4 xm4[BAND * 14];   // raw x_mem band for PV (10.5 KB)
    __shared__ float  fm[BAND][LDW];    // f_mem band            (25.3 KB)
    __shared__ float  fi[BR][LDW];      // f_in chunk            (16.9 KB)

    const int tid    = threadIdx.x;
    const int wave   = tid >> 6;
    const int lane   = tid & 63;
    const int chunks = NPTS / BR;       // 64
    const int b      = blockIdx.x / chunks;
    const int c0     = (blockIdx.x - b * chunks) * BR;
    const int bbase  = b * NPTS;

    // ---- 1. stage raw x_mem band (coalesced float4); also warms L2 for 2.
    const float4* srcm = (const float4*)(x_mem + (long)bbase * LFEAT);
    for (int i = tid; i < BAND * 14; i += 512) {
        const int r = i / 14, q = i - r * 14;
        const int g = min(max(c0 - HALFW + r, 0), NPTS - 1);
        xm4[i] = srcm[g * 14 + q];
    }

    // ---- 2. features. wave: h-half = wave&1, rows r ≡ (wave>>1) (mod 4).
    // 80 f-rows: 0..47 = fm band, 48..79 = fi chunk. 20 rows per wave.
    const int h = ((wave & 1) << 6) | lane;
    float4 w4[14];
    #pragma unroll
    for (int q = 0; q < 14; ++q)
        w4[q] = ((const float4*)(conv_w + h * LFEAT))[q];
    const float sc = gamma[h] / sqrtf(bvar[h] + 1e-5f);
    const float sh = (conv_b[h] - bmean[h]) * sc + beta[h];

    const int r0 = wave >> 1;

    // row r -> global row pointer
    #define ROWPTR(r) ((r) < BAND \
        ? x_mem + (long)(bbase + min(max(c0 - HALFW + (r), 0), NPTS - 1)) * LFEAT \
        : x_in  + (long)(bbase + c0 + ((r) - BAND)) * LFEAT)

    float xv = (lane < LFEAT) ? ROWPTR(r0)[lane] : 0.0f;
    #pragma unroll 1
    for (int k = 0; k < 20; ++k) {
        const int r = r0 + 4 * k;
        float xnext = 0.0f;
        if (k < 19) {
            const float* p = ROWPTR(r + 4);
            xnext = (lane < LFEAT) ? p[lane] : 0.0f;   // prefetch next row
        }
        float a0 = 0.0f, a1 = 0.0f;                    // two FMA chains
        #pragma unroll
        for (int q = 0; q < 14; q += 2) {
            a0 = fmaf(__shfl(xv, 4*q + 0), w4[q].x, a0);
            a0 = fmaf(__shfl(xv, 4*q + 1), w4[q].y, a0);
            a0 = fmaf(__shfl(xv, 4*q + 2), w4[q].z, a0);
            a0 = fmaf(__shfl(xv, 4*q + 3), w4[q].w, a0);
            a1 = fmaf(__shfl(xv, 4*q + 4), w4[q+1].x, a1);
            a1 = fmaf(__shfl(xv, 4*q + 5), w4[q+1].y, a1);
            a1 = fmaf(__shfl(xv, 4*q + 6), w4[q+1].z, a1);
            a1 = fmaf(__shfl(xv, 4*q + 7), w4[q+1].w, a1);
        }
        float f = (a0 + a1) * sc + sh;
        f = (f >= 0.0f) ? f : 0.1f * f;                // LeakyReLU(0.1)
        if (r < BAND) fm[r][h] = f;                    // stride-1 over h: conflict-free
        else          fi[r - BAND][h] = f;
        xv = xnext;
    }
    #undef ROWPTR
    __syncthreads();

    // ---- 3. banded attention (identical structure to round 13)
    const int lh = lane & 31;
    const float* xmf = (const float*)xm4;  // band as floats [BAND*56]

    #pragma unroll
    for (int rr = 0; rr < 4; rr += 2) {
        const int l0   = wave * 4 + rr;            // local row, half 0
        const int lrow = l0 + (lane >> 5);         // this half's local row
        const int n    = c0 + lrow;                // row within batch

        const int  mw    = n - HALFW + lh;
        const int  mc    = min(max(mw, 0), NPTS - 1);
        const int  slot  = mc - c0 + HALFW;        // LDS band slot
        const bool valid = (lh < NEIGH) && (mw >= 0) && (mw < NPTS);

        float p = -1e30f;
        if (lh < NEIGH) {
            const float4* a  = (const float4*)&fi[lrow][0];  // half-uniform
            const float4* bb = (const float4*)&fm[slot][0];  // per-lane
            float4 A0 = {0.f,0.f,0.f,0.f}, A1 = {0.f,0.f,0.f,0.f};
            #pragma unroll
            for (int q = 0; q < 32; q += 2) {
                const float4 u0 = a[q],     v0 = bb[q];
                const float4 u1 = a[q + 1], v1 = bb[q + 1];
                A0.x = fmaf(u0.x, v0.x, A0.x); A0.y = fmaf(u0.y, v0.y, A0.y);
                A0.z = fmaf(u0.z, v0.z, A0.z); A0.w = fmaf(u0.w, v0.w, A0.w);
                A1.x = fmaf(u1.x, v1.x, A1.x); A1.y = fmaf(u1.y, v1.y, A1.y);
                A1.z = fmaf(u1.z, v1.z, A1.z); A1.w = fmaf(u1.w, v1.w, A1.w);
            }
            const float d = ((A0.x + A0.y) + (A0.z + A0.w))
                          + ((A1.x + A1.y) + (A1.z + A1.w));
            p = valid ? d : -1e30f;
        }

        // softmax within each 32-half (invalid lanes contribute exp -> 0)
        float mx = p;
        #pragma unroll
        for (int off = 16; off >= 1; off >>= 1)
            mx = fmaxf(mx, __shfl_xor(mx, off));
        const float e = expf(p - mx);
        float sum = e;
        #pragma unroll
        for (int off = 16; off >= 1; off >>= 1)
            sum += __shfl_xor(sum, off);
        const float pn = e / sum;

        // broadcast weights for both rows (compile-time lane -> v_readlane)
        float swA[NEIGH], swB[NEIGH];
        #pragma unroll
        for (int w = 0; w < NEIGH; ++w) {
            swA[w] = __shfl(pn, w);
            swB[w] = __shfl(pn, 32 + w);
        }

        // PV from staged raw x_mem band + blend; lanes 0..55
        if (lane < LFEAT) {
            float accA = 0.0f, accB = 0.0f;
            #pragma unroll
            for (int w = 0; w < NEIGH; ++w) {
                const int sA = min(max(c0 + l0     - HALFW + w, 0), NPTS - 1) - c0 + HALFW;
                const int sB = min(max(c0 + l0 + 1 - HALFW + w, 0), NPTS - 1) - c0 + HALFW;
                accA = fmaf(swA[w], xmf[sA * LFEAT + lane], accA);
                accB = fmaf(swB[w], xmf[sB * LFEAT + lane], accB);
            }
            const long oA = (long)(bbase + c0 + l0) * LFEAT + lane;
            out[oA]         = 0.5f * x_in[oA]         + 0.5f * accA;
            out[oA + LFEAT] = 0.5f * x_in[oA + LFEAT] + 0.5f * accB;
        }
    }
}

// ---------------------------------------------------------------------------
extern "C" void kernel_launch(void* const* d_in, const int* in_sizes, int n_in,
                              void* d_out, int out_size, void* d_ws, size_t ws_size,
                              hipStream_t stream)
{
    const float* input  = (const float*)d_in[0];
    const float* smem   = (const float*)d_in[1];
    const float* conv_w = (const float*)d_in[2];
    const float* conv_b = (const float*)d_in[3];
    const float* gamma  = (const float*)d_in[4];
    const float* beta   = (const float*)d_in[5];
    const float* bmean  = (const float*)d_in[6];
    const float* bvar   = (const float*)d_in[7];
    float* out = (float*)d_out;

    const int R = in_sizes[0] / LFEAT;              // B*N = 16384
    const int blocks = (R / NPTS) * (NPTS / BR);    // 8 * 64 = 512

    fused_kernel<<<blocks, 512, 0, stream>>>(input, smem, conv_w, conv_b,
                                             gamma, beta, bmean, bvar, out, R);
}

// Round 16
// 95.357 us; speedup vs baseline: 1.4157x; 1.4157x over previous
//
#include <hip/hip_runtime.h>
#include <math.h>

#define NPTS   2048      // N
#define LFEAT  56        // C*L
#define HFEAT  128       // H
#define HALFW  8
#define BR     32        // q-rows per block
#define BAND   48        // BR + 2*HALFW
#define NROWS  80        // BAND (x_mem) + BR (x_in)
#define KPAD   64        // padded K for 56/48-dim contractions
#define SIMW   53        // sim row stride (odd -> conflict-free)

// Manual LDS layout (single 65,152 B block, phase-overlaid Region A):
//   S/F phase : x_hi | x_lo | w_hi | w_lo     (0 .. 53,248)
//   Q/M/P     : f_hi | f_lo | xmT             (0 .. 49,152, same region)
//   always    : sim | attn | sc | sh          (53,248 .. 65,152)
#define OFF_XH   0
#define OFF_XL   10240
#define OFF_WH   20480
#define OFF_WL   36864
#define OFF_FH   0
#define OFF_FL   20480
#define OFF_XMT  40960
#define OFF_SIM  53248
#define OFF_ATT  60032
#define OFF_SC   64128
#define OFF_SH   64640
#define SMEM_SZ  65152

typedef __bf16 bf16x8 __attribute__((ext_vector_type(8)));
typedef float  f32x4  __attribute__((ext_vector_type(4)));

__device__ __forceinline__ unsigned short f2bf(float f) {   // RTNE
    unsigned u = __builtin_bit_cast(unsigned, f);
    u += 0x7FFFu + ((u >> 16) & 1u);
    return (unsigned short)(u >> 16);
}
__device__ __forceinline__ float bf2f(unsigned short h) {
    unsigned u = ((unsigned)h) << 16;
    return __builtin_bit_cast(float, u);
}
__device__ __forceinline__ void split2(float v0, float v1, unsigned& hi, unsigned& lo) {
    const unsigned short h0 = f2bf(v0), h1 = f2bf(v1);
    hi = (unsigned)h0 | ((unsigned)h1 << 16);
    lo = (unsigned)f2bf(v0 - bf2f(h0)) | ((unsigned)f2bf(v1 - bf2f(h1)) << 16);
}
__device__ __forceinline__ unsigned pack2(float a, float b) {
    return (unsigned)f2bf(a) | ((unsigned)f2bf(b) << 16);
}
// XOR swizzle (G4): byte ^= (row&7)<<4; half- and dword-index forms.
__device__ __forceinline__ int swzH(int row, int halfIdx) { return halfIdx ^ ((row & 7) << 3); }
__device__ __forceinline__ int swzD(int row, int dwIdx)   { return dwIdx   ^ ((row & 7) << 2); }

// ---------------------------------------------------------------------------
__global__ __launch_bounds__(256) void fused_kernel(
    const float* __restrict__ x_in, const float* __restrict__ x_mem,
    const float* __restrict__ conv_w, const float* __restrict__ conv_b,
    const float* __restrict__ gamma,  const float* __restrict__ beta,
    const float* __restrict__ bmean,  const float* __restrict__ bvar,
    float* __restrict__ out, int R)
{
    __shared__ __align__(16) char smem[SMEM_SZ];
    unsigned short* x_h  = (unsigned short*)(smem + OFF_XH);
    unsigned short* x_l  = (unsigned short*)(smem + OFF_XL);
    unsigned short* w_h  = (unsigned short*)(smem + OFF_WH);
    unsigned short* w_l  = (unsigned short*)(smem + OFF_WL);
    unsigned short* f_h  = (unsigned short*)(smem + OFF_FH);
    unsigned short* f_l  = (unsigned short*)(smem + OFF_FL);
    unsigned short* xmT  = (unsigned short*)(smem + OFF_XMT);
    float*          siml = (float*)(smem + OFF_SIM);
    unsigned short* attl = (unsigned short*)(smem + OFF_ATT);
    float*          sc_l = (float*)(smem + OFF_SC);
    float*          sh_l = (float*)(smem + OFF_SH);

    const int tid  = threadIdx.x;
    const int wave = tid >> 6;
    const int lane = tid & 63;
    const int b     = blockIdx.x >> 6;              // NPTS/BR = 64 chunks/batch
    const int c0    = (blockIdx.x & 63) * BR;
    const int bbase = b * NPTS;

    // ---- S: BN fold + stage x (split hi/lo) + W (split hi/lo); K-pad zeroed
    if (tid < HFEAT) {
        const float s = gamma[tid] / sqrtf(bvar[tid] + 1e-5f);
        sc_l[tid] = s;
        sh_l[tid] = (conv_b[tid] - bmean[tid]) * s + beta[tid];
    }
    for (int i = tid; i < NROWS * 32; i += 256) {
        const int row = i >> 5, dp = i & 31, k = dp * 2;
        float v0 = 0.f, v1 = 0.f;
        if (k < LFEAT) {
            long g;
            const float* src;
            if (row < BAND) { g = bbase + min(max(c0 - HALFW + row, 0), NPTS - 1); src = x_mem; }
            else            { g = bbase + c0 + (row - BAND);                        src = x_in; }
            const float2 f2 = *(const float2*)(src + g * LFEAT + k);
            v0 = f2.x; v1 = f2.y;
        }
        unsigned hi, lo; split2(v0, v1, hi, lo);
        const int idx = swzD(row, row * 32 + dp);
        ((unsigned*)x_h)[idx] = hi;
        ((unsigned*)x_l)[idx] = lo;
    }
    for (int i = tid; i < HFEAT * 32; i += 256) {
        const int h = i >> 5, dp = i & 31, k = dp * 2;
        float v0 = 0.f, v1 = 0.f;
        if (k < LFEAT) {
            const float2 f2 = *(const float2*)(conv_w + h * LFEAT + k);
            v0 = f2.x; v1 = f2.y;
        }
        unsigned hi, lo; split2(v0, v1, hi, lo);
        const int idx = swzD(h, h * 32 + dp);
        ((unsigned*)w_h)[idx] = hi;
        ((unsigned*)w_l)[idx] = lo;
    }
    __syncthreads();                                 // bar1

    // ---- F: [80xK56] x [K56x128], split-bf16 (3 MFMA/tile-pair)
    f32x4 facc[5][2] = {};
    #pragma unroll
    for (int ks = 0; ks < 2; ++ks) {
        const int k0 = (lane >> 4) * 8 + ks * 32;
        bf16x8 ah[5], al[5];
        #pragma unroll
        for (int m = 0; m < 5; ++m) {
            const int row = m * 16 + (lane & 15);
            const int idx = swzH(row, row * KPAD + k0);
            ah[m] = *(const bf16x8*)(x_h + idx);
            al[m] = *(const bf16x8*)(x_l + idx);
        }
        #pragma unroll
        for (int nt = 0; nt < 2; ++nt) {
            const int h   = (wave * 2 + nt) * 16 + (lane & 15);
            const int idx = swzH(h, h * KPAD + k0);
            const bf16x8 bh = *(const bf16x8*)(w_h + idx);
            const bf16x8 bl = *(const bf16x8*)(w_l + idx);
            #pragma unroll
            for (int m = 0; m < 5; ++m) {
                facc[m][nt] = __builtin_amdgcn_mfma_f32_16x16x32_bf16(ah[m], bh, facc[m][nt], 0, 0, 0);
                facc[m][nt] = __builtin_amdgcn_mfma_f32_16x16x32_bf16(ah[m], bl, facc[m][nt], 0, 0, 0);
                facc[m][nt] = __builtin_amdgcn_mfma_f32_16x16x32_bf16(al[m], bh, facc[m][nt], 0, 0, 0);
            }
        }
    }
    __syncthreads();                                 // bar2a: F reads done, Region A free

    // BN + LeakyReLU in-register, write f as hi+lo bf16 (overlay region)
    #pragma unroll
    for (int nt = 0; nt < 2; ++nt) {
        const int h = (wave * 2 + nt) * 16 + (lane & 15);
        const float s = sc_l[h], t = sh_l[h];
        #pragma unroll
        for (int m = 0; m < 5; ++m) {
            #pragma unroll
            for (int r = 0; r < 4; ++r) {
                const int row = m * 16 + (lane >> 4) * 4 + r;
                float f = facc[m][nt][r] * s + t;
                f = (f >= 0.f) ? f : 0.1f * f;
                const unsigned short fh16 = f2bf(f);
                const int idx = swzH(row, row * HFEAT + h);
                f_h[idx] = fh16;
                f_l[idx] = f2bf(f - bf2f(fh16));
            }
        }
    }
    __syncthreads();                                 // bar2b

    // ---- Q: waves 0-1 QK (split-bf16); waves 2-3 stage xmT (bf16 single)
    if (wave < 2) {
        f32x4 qacc[3] = {};
        #pragma unroll
        for (int ks = 0; ks < 4; ++ks) {
            const int k0   = (lane >> 4) * 8 + ks * 32;
            const int arow = BAND + wave * 16 + (lane & 15);
            const int aidx = swzH(arow, arow * HFEAT + k0);
            const bf16x8 afh = *(const bf16x8*)(f_h + aidx);
            const bf16x8 afl = *(const bf16x8*)(f_l + aidx);
            #pragma unroll
            for (int nt = 0; nt < 3; ++nt) {
                const int kv   = nt * 16 + (lane & 15);
                const int bidx = swzH(kv, kv * HFEAT + k0);
                const bf16x8 bfh = *(const bf16x8*)(f_h + bidx);
                const bf16x8 bfl = *(const bf16x8*)(f_l + bidx);
                qacc[nt] = __builtin_amdgcn_mfma_f32_16x16x32_bf16(afh, bfh, qacc[nt], 0, 0, 0);
                qacc[nt] = __builtin_amdgcn_mfma_f32_16x16x32_bf16(afh, bfl, qacc[nt], 0, 0, 0);
                qacc[nt] = __builtin_amdgcn_mfma_f32_16x16x32_bf16(afl, bfh, qacc[nt], 0, 0, 0);
            }
        }
        #pragma unroll
        for (int nt = 0; nt < 3; ++nt) {
            #pragma unroll
            for (int r = 0; r < 4; ++r) {
                const int qr = wave * 16 + (lane >> 4) * 4 + r;
                siml[qr * SIMW + nt * 16 + (lane & 15)] = qacc[nt][r];
            }
        }
    } else {
        for (int i = tid - 128; i < KPAD * 32; i += 128) {
            const int j = i >> 5, dp = i & 31, k0 = dp * 2;
            float v0 = 0.f, v1 = 0.f;
            if (j < LFEAT) {
                if (k0 < BAND) {
                    const int g = min(max(c0 - HALFW + k0, 0), NPTS - 1);
                    v0 = x_mem[(long)(bbase + g) * LFEAT + j];
                }
                if (k0 + 1 < BAND) {
                    const int g = min(max(c0 - HALFW + k0 + 1, 0), NPTS - 1);
                    v1 = x_mem[(long)(bbase + g) * LFEAT + j];
                }
            }
            ((unsigned*)xmT)[swzD(j, j * 32 + dp)] = pack2(v0, v1);
        }
    }
    __syncthreads();                                 // bar3

    // ---- M: banded softmax, 32 threads, fp32 (clamp-mask semantics)
    if (tid < BR) {
        const int r = tid, n = c0 + r;
        float mx = -1e30f;
        #pragma unroll 1
        for (int jj = 0; jj <= 16; ++jj) {
            const int kv = n - HALFW + jj;
            if (kv >= 0 && kv < NPTS) mx = fmaxf(mx, siml[r * SIMW + r + jj]);
        }
        float sum = 0.f;
        #pragma unroll 1
        for (int jj = 0; jj <= 16; ++jj) {
            const int kv = n - HALFW + jj;
            if (kv >= 0 && kv < NPTS) sum += expf(siml[r * SIMW + r + jj] - mx);
        }
        const float inv = 1.0f / sum;
        #pragma unroll 1
        for (int dp = 0; dp < 32; ++dp) {
            const int j0 = dp * 2, j1 = dp * 2 + 1;
            float w0 = 0.f, w1 = 0.f;
            const int kv0 = c0 - HALFW + j0, kv1 = c0 - HALFW + j1;
            if (j0 >= r && j0 <= r + 16 && kv0 >= 0 && kv0 < NPTS)
                w0 = expf(siml[r * SIMW + j0] - mx) * inv;
            if (j1 >= r && j1 <= r + 16 && kv1 >= 0 && kv1 < NPTS)
                w1 = expf(siml[r * SIMW + j1] - mx) * inv;
            ((unsigned*)attl)[swzD(r, r * 32 + dp)] = pack2(w0, w1);
        }
    }
    __syncthreads();                                 // bar4

    // ---- P: PV (bf16) + blend
    {
        const int mw = wave & 1, tb = (wave >> 1) * 2;
        f32x4 pacc[2] = {};
        #pragma unroll
        for (int ks = 0; ks < 2; ++ks) {
            const int k0   = (lane >> 4) * 8 + ks * 32;
            const int arow = mw * 16 + (lane & 15);
            const bf16x8 af = *(const bf16x8*)(attl + swzH(arow, arow * KPAD + k0));
            #pragma unroll
            for (int t = 0; t < 2; ++t) {
                const int j = (tb + t) * 16 + (lane & 15);
                const bf16x8 bf = *(const bf16x8*)(xmT + swzH(j, j * KPAD + k0));
                pacc[t] = __builtin_amdgcn_mfma_f32_16x16x32_bf16(af, bf, pacc[t], 0, 0, 0);
            }
        }
        #pragma unroll
        for (int t = 0; t < 2; ++t) {
            const int j = (tb + t) * 16 + (lane & 15);
            if (j < LFEAT) {
                #pragma unroll
                for (int r = 0; r < 4; ++r) {
                    const int qr = mw * 16 + (lane >> 4) * 4 + r;
                    const long idx = (long)(bbase + c0 + qr) * LFEAT + j;
                    out[idx] = 0.5f * x_in[idx] + 0.5f * pacc[t][r];
                }
            }
        }
    }
}

// ---------------------------------------------------------------------------
extern "C" void kernel_launch(void* const* d_in, const int* in_sizes, int n_in,
                              void* d_out, int out_size, void* d_ws, size_t ws_size,
                              hipStream_t stream)
{
    const float* input  = (const float*)d_in[0];
    const float* smem   = (const float*)d_in[1];
    const float* conv_w = (const float*)d_in[2];
    const float* conv_b = (const float*)d_in[3];
    const float* gamma  = (const float*)d_in[4];
    const float* beta   = (const float*)d_in[5];
    const float* bmean  = (const float*)d_in[6];
    const float* bvar   = (const float*)d_in[7];
    float* out = (float*)d_out;

    const int R = in_sizes[0] / LFEAT;              // B*N = 16384
    const int blocks = (R / NPTS) * (NPTS / BR);    // 8 * 64 = 512

    fused_kernel<<<blocks, 256, 0, stream>>>(input, smem, conv_w, conv_b,
                                             gamma, beta, bmean, bvar, out, R);
}